// Round 12
// baseline (123.973 us; speedup 1.0000x reference)
//
#include <hip/hip_runtime.h>

// Single-head causal attention. Round 12: 1-batch 256-thread blocks ->
// 4 independent barrier domains per CU at 16 waves/CU. x global->reg
// (lane-private, 3 chunks in flight); wt via linear global_load_lds dbuf
// (24 KB LDS, parking aliases). Uniform derived vmcnt(7).
// B=2048, T=64, C=768, H=64. Inputs fp32: x, Wk, Wq, Wv ([in,out] layout).

#define BATCHES 2048
#define SEQ 64
#define CDIM 768
#define HDIM 64
#define NCX 24  // 768 / 32

typedef __bf16 bf16x8 __attribute__((ext_vector_type(8)));
typedef float f32x4v __attribute__((ext_vector_type(4)));
typedef unsigned short u16x8 __attribute__((ext_vector_type(8)));

__device__ __forceinline__ unsigned short f2bf(float f) {
  return __builtin_bit_cast(unsigned short, (__bf16)f);
}

// XOR swizzle for 64-elem bf16 parking rows: elem col ^= ((row&7)<<3)
__device__ __forceinline__ int swz(int row, int col) {
  return row * 64 + (col ^ ((row & 7) << 3));
}

__device__ __forceinline__ f32x4v mfma16(bf16x8 a, bf16x8 b, f32x4v c) {
  return __builtin_amdgcn_mfma_f32_16x16x32_bf16(a, b, c, 0, 0, 0);
}

__device__ __forceinline__ bf16x8 lds_frag(const unsigned short* p, int row, int col) {
  return __builtin_bit_cast(bf16x8, *reinterpret_cast<const u16x8*>(p + swz(row, col)));
}

__device__ __forceinline__ void gl_lds16(const void* g, void* l) {
  __builtin_amdgcn_global_load_lds(
      (const __attribute__((address_space(1))) void*)g,
      (__attribute__((address_space(3))) void*)l, 16, 0, 0);
}

// Prep (verified R4/R5/R7/R10): chunk-major, chunk stride 12288 B.
// ws element i: c = i/6144, slot = (i%6144)>>3, e = i&7;
// row = slot>>2 (mat*64+h), p = slot&3, g = p^((row>>1)&3), k = c*32+g*8+e.
__global__ __launch_bounds__(256) void prep_wt_kernel(
    const float* __restrict__ Wk, const float* __restrict__ Wq,
    const float* __restrict__ Wv, unsigned short* __restrict__ wt) {
  int i = blockIdx.x * 256 + threadIdx.x;
  if (i >= 3 * HDIM * CDIM) return;
  int c = i / 6144;
  int r2 = i - c * 6144;
  int slot = r2 >> 3;
  int e = r2 & 7;
  int row = slot >> 2;
  int p = slot & 3;
  int g = p ^ ((row >> 1) & 3);
  int k = c * 32 + g * 8 + e;
  int mat = row >> 6;
  int h = row & 63;
  const float* W = (mat == 0) ? Wq : ((mat == 1) ? Wk : Wv);
  wt[i] = f2bf(W[k * HDIM + h]);
}

__global__ __launch_bounds__(256, 4) void head_fused_kernel(
    const float* __restrict__ x, const unsigned short* __restrict__ wt,
    float* __restrict__ out) {
  const int bid = blockIdx.x;        // batch bid
  const int tid = threadIdx.x;
  const int w = tid >> 6;            // wave 0..3: rows [16w, 16w+16)
  const int lane = tid & 63;
  const int lane15 = lane & 15;
  const int lhi = lane >> 4;

  // LDS 24 KB: wt dbuf [wb0 12K][wb1 12K] during streaming;
  // parking aliases afterwards: [k 8K][vT 8K][qp 8K].
  __shared__ __align__(16) unsigned char smem[24576];

  // ---- wt staging: chunk = 12 regions x 1KB; wave w does regions {w,4+w,8+w}
  const char* wb0 = (const char*)wt + ((0 * 4 + w) * 64 + lane) * 16;
  const char* wb1 = (const char*)wt + ((1 * 4 + w) * 64 + lane) * 16;
  const char* wb2 = (const char*)wt + ((2 * 4 + w) * 64 + lane) * 16;
  const int wd0 = ((0 * 4 + w) * 64 + lane) * 16;
  const int wd1 = ((1 * 4 + w) * 64 + lane) * 16;
  const int wd2 = ((2 * 4 + w) * 64 + lane) * 16;

  #define STAGE_WT(cn, B)                                                   \
    do {                                                                    \
      char* wbp = (char*)smem + (B) * 12288;                                \
      gl_lds16(wb0 + (cn) * 12288, wbp + wd0);                              \
      gl_lds16(wb1 + (cn) * 12288, wbp + wd1);                              \
      gl_lds16(wb2 + (cn) * 12288, wbp + wd2);                              \
    } while (0)

  // ---- x per-lane direct stream (R10-verified addressing, 1 batch) ---------
  const char* xlane = (const char*)x + (size_t)bid * 196608 +
                      (16 * w + lane15) * 3072 + lhi * 32;
  #define ISSUE_X(cn, D0, D1)                                               \
    do {                                                                    \
      D0 = *reinterpret_cast<const f32x4v*>(xlane + (cn) * 128);            \
      D1 = *reinterpret_cast<const f32x4v*>(xlane + (cn) * 128 + 16);       \
    } while (0)

  const f32x4v z4 = {0.f, 0.f, 0.f, 0.f};
  f32x4v accq[4], acck[4], accv[4];
  #pragma unroll
  for (int n = 0; n < 4; ++n) { accq[n] = z4; acck[n] = z4; accv[n] = z4; }

  #define COMPUTE(c, X0, X1)                                                \
    do {                                                                    \
      const unsigned short* ws =                                            \
          (const unsigned short*)((char*)smem + ((c) & 1) * 12288);         \
      u16x8 ar;                                                             \
      _Pragma("unroll")                                                     \
      for (int i = 0; i < 4; ++i) { ar[i] = f2bf(X0[i]); ar[4 + i] = f2bf(X1[i]); } \
      bf16x8 a = __builtin_bit_cast(bf16x8, ar);                            \
      _Pragma("unroll")                                                     \
      for (int n = 0; n < 4; ++n) {                                         \
        int brq = 0 * HDIM + 16 * n + lane15;                               \
        int bpq = lhi ^ ((brq >> 1) & 3);                                   \
        bf16x8 bq = __builtin_bit_cast(bf16x8,                              \
            *reinterpret_cast<const u16x8*>(ws + brq * 32 + bpq * 8));      \
        accq[n] = mfma16(a, bq, accq[n]);                                   \
        int brk = 1 * HDIM + 16 * n + lane15;                               \
        int bpk = lhi ^ ((brk >> 1) & 3);                                   \
        bf16x8 bk = __builtin_bit_cast(bf16x8,                              \
            *reinterpret_cast<const u16x8*>(ws + brk * 32 + bpk * 8));      \
        acck[n] = mfma16(a, bk, acck[n]);                                   \
        int brv = 2 * HDIM + 16 * n + lane15;                               \
        int bpv = lhi ^ ((brv >> 1) & 3);                                   \
        bf16x8 bv = __builtin_bit_cast(bf16x8,                              \
            *reinterpret_cast<const u16x8*>(ws + brv * 32 + bpv * 8));      \
        accv[n] = mfma16(a, bv, accv[n]);                                   \
      }                                                                     \
    } while (0)

  // Program order of VMEM issues: wt0,x0,wt1,x1,x2,[wt2,x3],[wt3,x4],...
  // ITER(c) stages wt(c+2), issues x(c+3). At ITER(c) entry the newest ops
  // after {x(c),wt(c)} are x(c+1)(2)+wt(c+1)(3)+x(c+2)(2) = 7 -> vmcnt(7).
  // Tail: c=22 -> 5, c=23 -> 0.
  #define ITER(c, X0, X1)                                                   \
    do {                                                                    \
      if ((c) <= 21)      asm volatile("s_waitcnt vmcnt(7)" ::: "memory");  \
      else if ((c) == 22) asm volatile("s_waitcnt vmcnt(5)" ::: "memory");  \
      else                asm volatile("s_waitcnt vmcnt(0)" ::: "memory");  \
      __builtin_amdgcn_sched_barrier(0);                                    \
      __builtin_amdgcn_s_barrier();                                         \
      COMPUTE(c, X0, X1);                                                   \
      asm volatile("s_waitcnt lgkmcnt(0)" ::: "memory");                    \
      __builtin_amdgcn_sched_barrier(0);                                    \
      __builtin_amdgcn_s_barrier();                                         \
      if ((c) + 2 < NCX) STAGE_WT((c) + 2, (c) & 1);                        \
      __builtin_amdgcn_sched_barrier(0);                                    \
      if ((c) + 3 < NCX) ISSUE_X((c) + 3, X0, X1);                          \
      __builtin_amdgcn_sched_barrier(0);                                    \
    } while (0)

  f32x4v PA0, PA1, PB0, PB1, PC0, PC1;

  // prologue: wt0, x0, wt1, x1, x2 (12 outstanding per wave)
  STAGE_WT(0, 0);
  __builtin_amdgcn_sched_barrier(0);
  ISSUE_X(0, PA0, PA1);
  __builtin_amdgcn_sched_barrier(0);
  STAGE_WT(1, 1);
  __builtin_amdgcn_sched_barrier(0);
  ISSUE_X(1, PB0, PB1);
  ISSUE_X(2, PC0, PC1);
  __builtin_amdgcn_sched_barrier(0);

  ITER(0, PA0, PA1);   ITER(1, PB0, PB1);   ITER(2, PC0, PC1);
  ITER(3, PA0, PA1);   ITER(4, PB0, PB1);   ITER(5, PC0, PC1);
  ITER(6, PA0, PA1);   ITER(7, PB0, PB1);   ITER(8, PC0, PC1);
  ITER(9, PA0, PA1);   ITER(10, PB0, PB1);  ITER(11, PC0, PC1);
  ITER(12, PA0, PA1);  ITER(13, PB0, PB1);  ITER(14, PC0, PC1);
  ITER(15, PA0, PA1);  ITER(16, PB0, PB1);  ITER(17, PC0, PC1);
  ITER(18, PA0, PA1);  ITER(19, PB0, PB1);  ITER(20, PC0, PC1);
  ITER(21, PA0, PA1);  ITER(22, PB0, PB1);  ITER(23, PC0, PC1);

  #undef ITER
  #undef COMPUTE
  #undef ISSUE_X
  #undef STAGE_WT

  // ---- epilogue (verified): parking + phases 2-5 ----------------------------
  unsigned short* k_lds  = (unsigned short*)smem;
  unsigned short* vT_lds = (unsigned short*)(smem + 8192);
  unsigned short* qp_lds = (unsigned short*)(smem + 16384);

  // C/D layout: col = lane&15, row = (lane>>4)*4 + j   [measured m89/m91]
  #pragma unroll
  for (int n = 0; n < 4; ++n) {
    int h = 16 * n + lane15;
    #pragma unroll
    for (int j = 0; j < 4; ++j) {
      int s = 16 * w + lhi * 4 + j;
      k_lds[swz(s, h)] = f2bf(acck[n][j]);
      vT_lds[swz(h, s)] = f2bf(accv[n][j]);
      qp_lds[swz(s, h)] = f2bf(accq[n][j]);
    }
  }
  __syncthreads();

  // phase 2: S = q k^T
  const int trow = 16 * w + lane15;
  bf16x8 aq0 = lds_frag(qp_lds, trow, lhi * 8);
  bf16x8 aq1 = lds_frag(qp_lds, trow, 32 + lhi * 8);
  f32x4v accS[4];
  #pragma unroll
  for (int n = 0; n < 4; ++n) accS[n] = z4;
  #pragma unroll
  for (int sB = 0; sB < 4; ++sB) {
    if (sB <= w) {  // causal: col blocks above the diagonal are all-masked
      bf16x8 bk0 = lds_frag(k_lds, 16 * sB + lane15, lhi * 8);
      bf16x8 bk1 = lds_frag(k_lds, 16 * sB + lane15, 32 + lhi * 8);
      accS[sB] = mfma16(aq0, bk0, accS[sB]);
      accS[sB] = mfma16(aq1, bk1, accS[sB]);
    }
  }

  // phase 3: fp32 causal softmax, P -> bf16 LDS
  float rinv[4];
  #pragma unroll
  for (int j = 0; j < 4; ++j) {
    int t = 16 * w + lhi * 4 + j;
    float zv[4];
    float m = -3.0e38f;
    #pragma unroll
    for (int sB = 0; sB < 4; ++sB) {
      int sc = 16 * sB + lane15;
      float zz = (sB <= w && sc <= t) ? accS[sB][j] * 0.125f : -3.0e38f;
      zv[sB] = zz;
      m = fmaxf(m, zz);
    }
    #pragma unroll
    for (int off = 1; off < 16; off <<= 1) m = fmaxf(m, __shfl_xor(m, off));
    float sum = 0.f;
    float pv[4];
    #pragma unroll
    for (int sB = 0; sB < 4; ++sB) {
      float pe = __expf(zv[sB] - m);  // masked -> exp(-huge) = 0
      pv[sB] = pe;
      sum += pe;
    }
    #pragma unroll
    for (int off = 1; off < 16; off <<= 1) sum += __shfl_xor(sum, off);
    rinv[j] = 1.0f / sum;
    #pragma unroll
    for (int sB = 0; sB < 4; ++sB)
      qp_lds[swz(t, 16 * sB + lane15)] = f2bf(pv[sB]);
  }
  __syncthreads();  // P visible before A-frag reads

  // phase 4: O = P V
  f32x4v accO[4];
  #pragma unroll
  for (int n = 0; n < 4; ++n) accO[n] = z4;
  #pragma unroll
  for (int s0 = 0; s0 < 64; s0 += 32) {
    if (s0 <= 16 * w + 15) {  // causal: later s-blocks all zero for this wave
      bf16x8 ap = lds_frag(qp_lds, trow, s0 + lhi * 8);
      #pragma unroll
      for (int n = 0; n < 4; ++n) {
        bf16x8 bv = lds_frag(vT_lds, 16 * n + lane15, s0 + lhi * 8);
        accO[n] = mfma16(ap, bv, accO[n]);
      }
    }
  }

  // phase 5: normalize + store fp32
  float* op = out + (size_t)bid * (SEQ * HDIM);
  #pragma unroll
  for (int n = 0; n < 4; ++n) {
    int h = 16 * n + lane15;
    #pragma unroll
    for (int j = 0; j < 4; ++j) {
      int t = 16 * w + lhi * 4 + j;
      op[t * HDIM + h] = accO[n][j] * rinv[j];
    }
  }
}

extern "C" void kernel_launch(void* const* d_in, const int* in_sizes, int n_in,
                              void* d_out, int out_size, void* d_ws, size_t ws_size,
                              hipStream_t stream) {
  const float* x  = (const float*)d_in[0];
  const float* Wk = (const float*)d_in[1];
  const float* Wq = (const float*)d_in[2];
  const float* Wv = (const float*)d_in[3];
  float* out = (float*)d_out;
  unsigned short* wt = (unsigned short*)d_ws;  // 24 chunks x 12 KB = 288 KiB

  hipLaunchKernelGGL(prep_wt_kernel, dim3((3 * HDIM * CDIM + 255) / 256), dim3(256),
                     0, stream, Wk, Wq, Wv, wt);
  hipLaunchKernelGGL(head_fused_kernel, dim3(BATCHES), dim3(256), 0, stream,
                     x, wt, out);
}

// Round 13
// 106.452 us; speedup vs baseline: 1.1646x; 1.1646x over previous
//
#include <hip/hip_runtime.h>

// Single-head causal attention — FINAL (best measured config, from Round 5):
// 2-batch 512-thread blocks, 3-deep x pipeline + 2-deep wt pipeline with
// derived counted vmcnt; verified swizzled staging and MFMA layouts.
// B=2048, T=64, C=768, H=64. Inputs fp32: x, Wk, Wq, Wv ([in,out] layout).

#define BATCHES 2048
#define SEQ 64
#define CDIM 768
#define HDIM 64
#define NCHUNK 24  // 768 / 32

typedef __bf16 bf16x8 __attribute__((ext_vector_type(8)));
typedef float f32x4v __attribute__((ext_vector_type(4)));
typedef unsigned short u16x8 __attribute__((ext_vector_type(8)));

__device__ __forceinline__ unsigned short f2bf(float f) {
  return __builtin_bit_cast(unsigned short, (__bf16)f);
}

// XOR swizzle for 64-elem bf16 parking rows: elem col ^= ((row&7)<<3)
__device__ __forceinline__ int swz(int row, int col) {
  return row * 64 + (col ^ ((row & 7) << 3));
}

__device__ __forceinline__ f32x4v mfma16(bf16x8 a, bf16x8 b, f32x4v c) {
  return __builtin_amdgcn_mfma_f32_16x16x32_bf16(a, b, c, 0, 0, 0);
}

__device__ __forceinline__ bf16x8 lds_frag(const unsigned short* p, int row, int col) {
  return __builtin_bit_cast(bf16x8, *reinterpret_cast<const u16x8*>(p + swz(row, col)));
}

__device__ __forceinline__ void gl_lds16(const void* g, void* l) {
  __builtin_amdgcn_global_load_lds(
      (const __attribute__((address_space(1))) void*)g,
      (__attribute__((address_space(3))) void*)l, 16, 0, 0);
}

// Prep: ws chunk = 16 KB (8192 shorts): [slot 0..1023][e 0..7].
// slots 768..1023 are padding (never read from LDS). For slot<768:
// row = slot>>2 (mat*64+h), p = slot&3, g = p^((row>>1)&3), k = c*32+g*8+e.
__global__ __launch_bounds__(256) void prep_wt_kernel(
    const float* __restrict__ Wk, const float* __restrict__ Wq,
    const float* __restrict__ Wv, unsigned short* __restrict__ wt) {
  int i = blockIdx.x * 256 + threadIdx.x;
  if (i >= NCHUNK * 8192) return;
  int c = i >> 13;
  int r2 = i & 8191;
  int slot = r2 >> 3;
  if (slot >= 768) return;  // padding region: leave as-is (never consumed)
  int e = r2 & 7;
  int row = slot >> 2;
  int p = slot & 3;
  int g = p ^ ((row >> 1) & 3);
  int k = c * 32 + g * 8 + e;
  int mat = row >> 6;
  int h = row & 63;
  const float* W = (mat == 0) ? Wq : ((mat == 1) ? Wk : Wv);
  wt[i] = f2bf(W[k * HDIM + h]);
}

__global__ __launch_bounds__(512) void head_fused_kernel(
    const float* __restrict__ x, const unsigned short* __restrict__ wt,
    float* __restrict__ out) {
  const int bid = blockIdx.x;        // handles batches 2*bid, 2*bid+1
  const int tid = threadIdx.x;
  const int w = tid >> 6;            // wave 0..7
  const int ww = w & 3;              // wave-in-batch: rows [16ww, 16ww+16)
  const int bat = w >> 2;            // 0/1
  const int lane = tid & 63;
  const int lane15 = lane & 15;
  const int lhi = lane >> 4;

  // LDS 80 KB: [xb0 16K @0][xb1 @16K][xb2 @32K][wb0 @48K][wb1 @64K].
  // Parking (after streaming): batch r at r*24576: [k 8K][vT 8K][qp 8K].
  __shared__ __align__(16) unsigned char smem[81920];

  // ---- staging addresses ----------------------------------------------------
  // x chunk image per buffer: [batch r 8K][row 0..63][phys granule 0..7]x16B,
  // phys granule p holds logical granule p^(row&7); source pre-swizzled.
  const char* xsrc0;  // r = 0 -> batch 2*bid
  const char* xsrc1;  // r = 1 -> batch 2*bid+1
  {
    int s = w * 64 + lane;          // 0..511
    int row = s >> 3;
    int p = s & 7;
    size_t boff = row * (CDIM * 4) + ((p ^ (row & 7)) * 16);
    xsrc0 = (const char*)x + (size_t)(2 * bid + 0) * (SEQ * CDIM * 4) + boff;
    xsrc1 = (const char*)x + (size_t)(2 * bid + 1) * (SEQ * CDIM * 4) + boff;
  }
  const int xdst = (w * 64 + lane) * 16;  // within batch-r half: r*8192 + xdst

  // wt: fully linear (pre-swizzled in ws), chunk stride 16384 B.
  const char* wsrc0 = (const char*)wt + ((0 * 512 + w * 64 + lane) * 16);
  const char* wsrc1 = (const char*)wt + ((1 * 512 + w * 64 + lane) * 16);
  const int wdst0 = (0 * 512 + w * 64 + lane) * 16;
  const int wdst1 = (1 * 512 + w * 64 + lane) * 16;

  #define STAGE_X(cn, B)                                                    \
    do {                                                                    \
      char* xbp = (char*)smem + (B) * 16384;                                \
      gl_lds16(xsrc0 + (cn) * 128, xbp + 0 * 8192 + xdst);                  \
      gl_lds16(xsrc1 + (cn) * 128, xbp + 1 * 8192 + xdst);                  \
    } while (0)
  #define STAGE_W(cn, B)                                                    \
    do {                                                                    \
      char* wbp = (char*)smem + 49152 + (B) * 16384;                        \
      gl_lds16(wsrc0 + (cn) * 16384, wbp + wdst0);                          \
      gl_lds16(wsrc1 + (cn) * 16384, wbp + wdst1);                          \
    } while (0)

  const f32x4v z4 = {0.f, 0.f, 0.f, 0.f};
  f32x4v accq[4], acck[4], accv[4];
  #pragma unroll
  for (int n = 0; n < 4; ++n) { accq[n] = z4; acck[n] = z4; accv[n] = z4; }

  const int arow = 16 * ww + lane15;
  const int ag0 = (lhi * 2) ^ (arow & 7);
  const int ag1 = (lhi * 2 + 1) ^ (arow & 7);
  const int batoff = bat * 8192;

  // prologue (issue order defines the vm queue): W0,X0,W1,X1,X2
  STAGE_W(0, 0);
  STAGE_X(0, 0);
  STAGE_W(1, 1);
  STAGE_X(1, 1);
  STAGE_X(2, 2);

  #pragma unroll
  for (int c = 0; c < NCHUNK; ++c) {
    // derived waits: complete through {x(c), w(c)}; keep newer loads in flight
    if (c <= NCHUNK - 3)      asm volatile("s_waitcnt vmcnt(6)" ::: "memory");
    else if (c == NCHUNK - 2) asm volatile("s_waitcnt vmcnt(4)" ::: "memory");
    else                      asm volatile("s_waitcnt vmcnt(0)" ::: "memory");
    __builtin_amdgcn_s_barrier();

    {  // compute chunk c
      const float* xs = (const float*)((char*)smem + (c % 3) * 16384 + batoff);
      const unsigned short* ws =
          (const unsigned short*)((char*)smem + 49152 + (c & 1) * 16384);
      f32x4v xa = *reinterpret_cast<const f32x4v*>(xs + arow * 32 + ag0 * 4);
      f32x4v xb4 = *reinterpret_cast<const f32x4v*>(xs + arow * 32 + ag1 * 4);
      u16x8 ar;
      #pragma unroll
      for (int i = 0; i < 4; ++i) { ar[i] = f2bf(xa[i]); ar[4 + i] = f2bf(xb4[i]); }
      bf16x8 a = __builtin_bit_cast(bf16x8, ar);
      #pragma unroll
      for (int n = 0; n < 4; ++n) {
        int brq = 0 * HDIM + 16 * n + lane15;
        int bpq = lhi ^ ((brq >> 1) & 3);
        bf16x8 bq = __builtin_bit_cast(bf16x8,
            *reinterpret_cast<const u16x8*>(ws + brq * 32 + bpq * 8));
        accq[n] = mfma16(a, bq, accq[n]);
        int brk = 1 * HDIM + 16 * n + lane15;
        int bpk = lhi ^ ((brk >> 1) & 3);
        bf16x8 bk = __builtin_bit_cast(bf16x8,
            *reinterpret_cast<const u16x8*>(ws + brk * 32 + bpk * 8));
        acck[n] = mfma16(a, bk, acck[n]);
        int brv = 2 * HDIM + 16 * n + lane15;
        int bpv = lhi ^ ((brv >> 1) & 3);
        bf16x8 bv = __builtin_bit_cast(bf16x8,
            *reinterpret_cast<const u16x8*>(ws + brv * 32 + bpv * 8));
        accv[n] = mfma16(a, bv, accv[n]);
      }
    }

    asm volatile("s_waitcnt lgkmcnt(0)" ::: "memory");
    __builtin_amdgcn_s_barrier();

    // refill the buffers just freed (W before X: keeps queue order invariant)
    if (c + 2 < NCHUNK) STAGE_W(c + 2, c & 1);
    if (c + 3 < NCHUNK) STAGE_X(c + 3, c % 3);
  }

  #undef STAGE_X
  #undef STAGE_W

  // ---- parking: k, vT, q as bf16 in swizzled LDS (aliases x buffers) --------
  // C/D layout: col = lane&15, row = (lane>>4)*4 + j   [measured m89/m91]
  unsigned short* k_lds  = (unsigned short*)((char*)smem + bat * 24576);
  unsigned short* vT_lds = (unsigned short*)((char*)smem + bat * 24576 + 8192);
  unsigned short* qp_lds = (unsigned short*)((char*)smem + bat * 24576 + 16384);
  #pragma unroll
  for (int n = 0; n < 4; ++n) {
    int h = 16 * n + lane15;
    #pragma unroll
    for (int j = 0; j < 4; ++j) {
      int s = 16 * ww + lhi * 4 + j;
      k_lds[swz(s, h)] = f2bf(acck[n][j]);
      vT_lds[swz(h, s)] = f2bf(accv[n][j]);
      qp_lds[swz(s, h)] = f2bf(accq[n][j]);
    }
  }
  __syncthreads();

  // ---------------- phase 2: S = q k^T (K over h) -----------------------------
  const int trow = 16 * ww + lane15;
  bf16x8 aq0 = lds_frag(qp_lds, trow, lhi * 8);
  bf16x8 aq1 = lds_frag(qp_lds, trow, 32 + lhi * 8);
  f32x4v accS[4];
  #pragma unroll
  for (int n = 0; n < 4; ++n) accS[n] = z4;
  #pragma unroll
  for (int sB = 0; sB < 4; ++sB) {
    if (sB <= ww) {  // causal: col blocks above the diagonal are all-masked
      bf16x8 bk0 = lds_frag(k_lds, 16 * sB + lane15, lhi * 8);
      bf16x8 bk1 = lds_frag(k_lds, 16 * sB + lane15, 32 + lhi * 8);
      accS[sB] = mfma16(aq0, bk0, accS[sB]);
      accS[sB] = mfma16(aq1, bk1, accS[sB]);
    }
  }

  // ---------------- phase 3: fp32 causal softmax, P -> bf16 LDS ---------------
  float rinv[4];
  #pragma unroll
  for (int j = 0; j < 4; ++j) {
    int t = 16 * ww + lhi * 4 + j;
    float zv[4];
    float m = -3.0e38f;
    #pragma unroll
    for (int sB = 0; sB < 4; ++sB) {
      int s = 16 * sB + lane15;
      float zz = (sB <= ww && s <= t) ? accS[sB][j] * 0.125f : -3.0e38f;
      zv[sB] = zz;
      m = fmaxf(m, zz);
    }
    #pragma unroll
    for (int off = 1; off < 16; off <<= 1) m = fmaxf(m, __shfl_xor(m, off));
    float sum = 0.f;
    float pv[4];
    #pragma unroll
    for (int sB = 0; sB < 4; ++sB) {
      float pe = __expf(zv[sB] - m);  // masked -> exp(-huge) = 0
      pv[sB] = pe;
      sum += pe;
    }
    #pragma unroll
    for (int off = 1; off < 16; off <<= 1) sum += __shfl_xor(sum, off);
    rinv[j] = 1.0f / sum;
    #pragma unroll
    for (int sB = 0; sB < 4; ++sB)
      qp_lds[swz(t, 16 * sB + lane15)] = f2bf(pv[sB]);
  }
  __syncthreads();  // P visible before A-frag reads

  // ---------------- phase 4: O = P V (K over s) -------------------------------
  f32x4v accO[4];
  #pragma unroll
  for (int n = 0; n < 4; ++n) accO[n] = z4;
  #pragma unroll
  for (int s0 = 0; s0 < 64; s0 += 32) {
    if (s0 <= 16 * ww + 15) {  // causal: later s-blocks all zero for this wave
      bf16x8 ap = lds_frag(qp_lds, trow, s0 + lhi * 8);
      #pragma unroll
      for (int n = 0; n < 4; ++n) {
        bf16x8 bv = lds_frag(vT_lds, 16 * n + lane15, s0 + lhi * 8);
        accO[n] = mfma16(ap, bv, accO[n]);
      }
    }
  }

  // ---------------- phase 5: normalize + store fp32 ---------------------------
  float* op = out + (size_t)(2 * bid + bat) * (SEQ * HDIM);
  #pragma unroll
  for (int n = 0; n < 4; ++n) {
    int h = 16 * n + lane15;
    #pragma unroll
    for (int j = 0; j < 4; ++j) {
      int t = 16 * ww + lhi * 4 + j;
      op[t * HDIM + h] = accO[n][j] * rinv[j];
    }
  }
}

extern "C" void kernel_launch(void* const* d_in, const int* in_sizes, int n_in,
                              void* d_out, int out_size, void* d_ws, size_t ws_size,
                              hipStream_t stream) {
  const float* x  = (const float*)d_in[0];
  const float* Wk = (const float*)d_in[1];
  const float* Wq = (const float*)d_in[2];
  const float* Wv = (const float*)d_in[3];
  float* out = (float*)d_out;
  unsigned short* wt = (unsigned short*)d_ws;  // 24 chunks x 16 KB = 384 KiB

  hipLaunchKernelGGL(prep_wt_kernel, dim3((NCHUNK * 8192 + 255) / 256), dim3(256),
                     0, stream, Wk, Wq, Wv, wt);
  hipLaunchKernelGGL(head_fused_kernel, dim3(BATCHES / 2), dim3(512), 0, stream,
                     x, wt, out);
}

// Round 14
// 103.344 us; speedup vs baseline: 1.1996x; 1.0301x over previous
//
#include <hip/hip_runtime.h>

// Single-head causal attention. Round 14: R13 (=R5 best) with the wt padding
// waste removed — 12 KB unpadded wt chunks staged via the R7-verified
// 1KB-region scheme (wave w: region w; waves 0-3 also region 8+w), per-wave
// asymmetric counted vmcnt. Cuts 98 MB of garbage DMA; LDS 80->72 KB.
// B=2048, T=64, C=768, H=64. Inputs fp32: x, Wk, Wq, Wv ([in,out] layout).

#define BATCHES 2048
#define SEQ 64
#define CDIM 768
#define HDIM 64
#define NCHUNK 24  // 768 / 32

typedef __bf16 bf16x8 __attribute__((ext_vector_type(8)));
typedef float f32x4v __attribute__((ext_vector_type(4)));
typedef unsigned short u16x8 __attribute__((ext_vector_type(8)));

__device__ __forceinline__ unsigned short f2bf(float f) {
  return __builtin_bit_cast(unsigned short, (__bf16)f);
}

// XOR swizzle for 64-elem bf16 parking rows: elem col ^= ((row&7)<<3)
__device__ __forceinline__ int swz(int row, int col) {
  return row * 64 + (col ^ ((row & 7) << 3));
}

__device__ __forceinline__ f32x4v mfma16(bf16x8 a, bf16x8 b, f32x4v c) {
  return __builtin_amdgcn_mfma_f32_16x16x32_bf16(a, b, c, 0, 0, 0);
}

__device__ __forceinline__ bf16x8 lds_frag(const unsigned short* p, int row, int col) {
  return __builtin_bit_cast(bf16x8, *reinterpret_cast<const u16x8*>(p + swz(row, col)));
}

__device__ __forceinline__ void gl_lds16(const void* g, void* l) {
  __builtin_amdgcn_global_load_lds(
      (const __attribute__((address_space(1))) void*)g,
      (__attribute__((address_space(3))) void*)l, 16, 0, 0);
}

// Prep (verified R4/R7/R10): chunk-major, chunk stride 12288 B (unpadded).
// ws element i: c = i/6144, slot = (i%6144)>>3, e = i&7;
// row = slot>>2 (mat*64+h), p = slot&3, g = p^((row>>1)&3), k = c*32+g*8+e.
__global__ __launch_bounds__(256) void prep_wt_kernel(
    const float* __restrict__ Wk, const float* __restrict__ Wq,
    const float* __restrict__ Wv, unsigned short* __restrict__ wt) {
  int i = blockIdx.x * 256 + threadIdx.x;
  if (i >= 3 * HDIM * CDIM) return;
  int c = i / 6144;
  int r2 = i - c * 6144;
  int slot = r2 >> 3;
  int e = r2 & 7;
  int row = slot >> 2;
  int p = slot & 3;
  int g = p ^ ((row >> 1) & 3);
  int k = c * 32 + g * 8 + e;
  int mat = row >> 6;
  int h = row & 63;
  const float* W = (mat == 0) ? Wq : ((mat == 1) ? Wk : Wv);
  wt[i] = f2bf(W[k * HDIM + h]);
}

__global__ __launch_bounds__(512) void head_fused_kernel(
    const float* __restrict__ x, const unsigned short* __restrict__ wt,
    float* __restrict__ out) {
  const int bid = blockIdx.x;        // handles batches 2*bid, 2*bid+1
  const int tid = threadIdx.x;
  const int w = tid >> 6;            // wave 0..7
  const int ww = w & 3;              // wave-in-batch: rows [16ww, 16ww+16)
  const int bat = w >> 2;            // 0/1
  const int lane = tid & 63;
  const int lane15 = lane & 15;
  const int lhi = lane >> 4;

  // LDS 72 KB: [xb0 16K @0][xb1 @16K][xb2 @32K][wb0 12K @48K][wb1 12K @60K].
  // Parking (after streaming): batch r at r*24576: [k 8K][vT 8K][qp 8K].
  __shared__ __align__(16) unsigned char smem[73728];

  // ---- staging addresses ----------------------------------------------------
  // x chunk image per buffer: [batch r 8K][row 0..63][phys granule 0..7]x16B,
  // phys granule p holds logical granule p^(row&7); source pre-swizzled.
  const char* xsrc0;  // r = 0 -> batch 2*bid
  const char* xsrc1;  // r = 1 -> batch 2*bid+1
  {
    int s = w * 64 + lane;          // 0..511
    int row = s >> 3;
    int p = s & 7;
    size_t boff = row * (CDIM * 4) + ((p ^ (row & 7)) * 16);
    xsrc0 = (const char*)x + (size_t)(2 * bid + 0) * (SEQ * CDIM * 4) + boff;
    xsrc1 = (const char*)x + (size_t)(2 * bid + 1) * (SEQ * CDIM * 4) + boff;
  }
  const int xdst = (w * 64 + lane) * 16;  // within batch-r half: r*8192 + xdst

  // wt: unpadded 12288-B chunks = 12 regions x 1 KB (64 lanes x 16B).
  // Wave w stages region w; waves 0..3 additionally stage region 8+w.
  // Dest = wave-uniform base + lane*16 (contract-safe).
  const char* wsrcA = (const char*)wt + (w * 64 + lane) * 16;
  const char* wsrcB = (const char*)wt + ((8 + w) * 64 + lane) * 16;
  const int wdstA = (w * 64 + lane) * 16;
  const int wdstB = ((8 + w) * 64 + lane) * 16;

  #define STAGE_X(cn, B)                                                    \
    do {                                                                    \
      char* xbp = (char*)smem + (B) * 16384;                                \
      gl_lds16(xsrc0 + (cn) * 128, xbp + 0 * 8192 + xdst);                  \
      gl_lds16(xsrc1 + (cn) * 128, xbp + 1 * 8192 + xdst);                  \
    } while (0)
  #define STAGE_W(cn, B)                                                    \
    do {                                                                    \
      char* wbp = (char*)smem + 49152 + (B) * 12288;                        \
      gl_lds16(wsrcA + (cn) * 12288, wbp + wdstA);                          \
      if (w < 4) gl_lds16(wsrcB + (cn) * 12288, wbp + wdstB);               \
    } while (0)

  const f32x4v z4 = {0.f, 0.f, 0.f, 0.f};
  f32x4v accq[4], acck[4], accv[4];
  #pragma unroll
  for (int n = 0; n < 4; ++n) { accq[n] = z4; acck[n] = z4; accv[n] = z4; }

  const int arow = 16 * ww + lane15;
  const int ag0 = (lhi * 2) ^ (arow & 7);
  const int ag1 = (lhi * 2 + 1) ^ (arow & 7);
  const int batoff = bat * 8192;

  // prologue (issue order defines the per-wave vm queue): W0,X0,W1,X1,X2
  STAGE_W(0, 0);
  STAGE_X(0, 0);
  STAGE_W(1, 1);
  STAGE_X(1, 1);
  STAGE_X(2, 2);

  #pragma unroll
  for (int c = 0; c < NCHUNK; ++c) {
    // Derived waits (per-wave queue; a = wt loads/chunk = 2 for waves 0-3,
    // 1 for waves 4-7). At entry: W(c)[a] X(c)[2] W(c+1)[a] X(c+1)[2] X(c+2)[2].
    // Wait through X(c): leave a+4 (steady), a+2 (c=22), 0 (c=23).
    if (c <= NCHUNK - 3) {
      if (w < 4) asm volatile("s_waitcnt vmcnt(6)" ::: "memory");
      else       asm volatile("s_waitcnt vmcnt(5)" ::: "memory");
    } else if (c == NCHUNK - 2) {
      if (w < 4) asm volatile("s_waitcnt vmcnt(4)" ::: "memory");
      else       asm volatile("s_waitcnt vmcnt(3)" ::: "memory");
    } else {
      asm volatile("s_waitcnt vmcnt(0)" ::: "memory");
    }
    __builtin_amdgcn_s_barrier();

    {  // compute chunk c
      const float* xs = (const float*)((char*)smem + (c % 3) * 16384 + batoff);
      const unsigned short* ws =
          (const unsigned short*)((char*)smem + 49152 + (c & 1) * 12288);
      f32x4v xa = *reinterpret_cast<const f32x4v*>(xs + arow * 32 + ag0 * 4);
      f32x4v xb4 = *reinterpret_cast<const f32x4v*>(xs + arow * 32 + ag1 * 4);
      u16x8 ar;
      #pragma unroll
      for (int i = 0; i < 4; ++i) { ar[i] = f2bf(xa[i]); ar[4 + i] = f2bf(xb4[i]); }
      bf16x8 a = __builtin_bit_cast(bf16x8, ar);
      #pragma unroll
      for (int n = 0; n < 4; ++n) {
        int brq = 0 * HDIM + 16 * n + lane15;
        int bpq = lhi ^ ((brq >> 1) & 3);
        bf16x8 bq = __builtin_bit_cast(bf16x8,
            *reinterpret_cast<const u16x8*>(ws + brq * 32 + bpq * 8));
        accq[n] = mfma16(a, bq, accq[n]);
        int brk = 1 * HDIM + 16 * n + lane15;
        int bpk = lhi ^ ((brk >> 1) & 3);
        bf16x8 bk = __builtin_bit_cast(bf16x8,
            *reinterpret_cast<const u16x8*>(ws + brk * 32 + bpk * 8));
        acck[n] = mfma16(a, bk, acck[n]);
        int brv = 2 * HDIM + 16 * n + lane15;
        int bpv = lhi ^ ((brv >> 1) & 3);
        bf16x8 bv = __builtin_bit_cast(bf16x8,
            *reinterpret_cast<const u16x8*>(ws + brv * 32 + bpv * 8));
        accv[n] = mfma16(a, bv, accv[n]);
      }
    }

    asm volatile("s_waitcnt lgkmcnt(0)" ::: "memory");
    __builtin_amdgcn_s_barrier();

    // refill the buffers just freed (W before X: keeps queue order invariant)
    if (c + 2 < NCHUNK) STAGE_W(c + 2, c & 1);
    if (c + 3 < NCHUNK) STAGE_X(c + 3, c % 3);
  }

  #undef STAGE_X
  #undef STAGE_W

  // ---- parking: k, vT, q as bf16 in swizzled LDS (aliases x buffers) --------
  // C/D layout: col = lane&15, row = (lane>>4)*4 + j   [measured m89/m91]
  unsigned short* k_lds  = (unsigned short*)((char*)smem + bat * 24576);
  unsigned short* vT_lds = (unsigned short*)((char*)smem + bat * 24576 + 8192);
  unsigned short* qp_lds = (unsigned short*)((char*)smem + bat * 24576 + 16384);
  #pragma unroll
  for (int n = 0; n < 4; ++n) {
    int h = 16 * n + lane15;
    #pragma unroll
    for (int j = 0; j < 4; ++j) {
      int s = 16 * ww + lhi * 4 + j;
      k_lds[swz(s, h)] = f2bf(acck[n][j]);
      vT_lds[swz(h, s)] = f2bf(accv[n][j]);
      qp_lds[swz(s, h)] = f2bf(accq[n][j]);
    }
  }
  __syncthreads();

  // ---------------- phase 2: S = q k^T (K over h) -----------------------------
  const int trow = 16 * ww + lane15;
  bf16x8 aq0 = lds_frag(qp_lds, trow, lhi * 8);
  bf16x8 aq1 = lds_frag(qp_lds, trow, 32 + lhi * 8);
  f32x4v accS[4];
  #pragma unroll
  for (int n = 0; n < 4; ++n) accS[n] = z4;
  #pragma unroll
  for (int sB = 0; sB < 4; ++sB) {
    if (sB <= ww) {  // causal: col blocks above the diagonal are all-masked
      bf16x8 bk0 = lds_frag(k_lds, 16 * sB + lane15, lhi * 8);
      bf16x8 bk1 = lds_frag(k_lds, 16 * sB + lane15, 32 + lhi * 8);
      accS[sB] = mfma16(aq0, bk0, accS[sB]);
      accS[sB] = mfma16(aq1, bk1, accS[sB]);
    }
  }

  // ---------------- phase 3: fp32 causal softmax, P -> bf16 LDS ---------------
  float rinv[4];
  #pragma unroll
  for (int j = 0; j < 4; ++j) {
    int t = 16 * ww + lhi * 4 + j;
    float zv[4];
    float m = -3.0e38f;
    #pragma unroll
    for (int sB = 0; sB < 4; ++sB) {
      int s = 16 * sB + lane15;
      float zz = (sB <= ww && s <= t) ? accS[sB][j] * 0.125f : -3.0e38f;
      zv[sB] = zz;
      m = fmaxf(m, zz);
    }
    #pragma unroll
    for (int off = 1; off < 16; off <<= 1) m = fmaxf(m, __shfl_xor(m, off));
    float sum = 0.f;
    float pv[4];
    #pragma unroll
    for (int sB = 0; sB < 4; ++sB) {
      float pe = __expf(zv[sB] - m);  // masked -> exp(-huge) = 0
      pv[sB] = pe;
      sum += pe;
    }
    #pragma unroll
    for (int off = 1; off < 16; off <<= 1) sum += __shfl_xor(sum, off);
    rinv[j] = 1.0f / sum;
    #pragma unroll
    for (int sB = 0; sB < 4; ++sB)
      qp_lds[swz(t, 16 * sB + lane15)] = f2bf(pv[sB]);
  }
  __syncthreads();  // P visible before A-frag reads

  // ---------------- phase 4: O = P V (K over s) -------------------------------
  f32x4v accO[4];
  #pragma unroll
  for (int n = 0; n < 4; ++n) accO[n] = z4;
  #pragma unroll
  for (int s0 = 0; s0 < 64; s0 += 32) {
    if (s0 <= 16 * ww + 15) {  // causal: later s-blocks all zero for this wave
      bf16x8 ap = lds_frag(qp_lds, trow, s0 + lhi * 8);
      #pragma unroll
      for (int n = 0; n < 4; ++n) {
        bf16x8 bv = lds_frag(vT_lds, 16 * n + lane15, s0 + lhi * 8);
        accO[n] = mfma16(ap, bv, accO[n]);
      }
    }
  }

  // ---------------- phase 5: normalize + store fp32 ---------------------------
  float* op = out + (size_t)(2 * bid + bat) * (SEQ * HDIM);
  #pragma unroll
  for (int n = 0; n < 4; ++n) {
    int h = 16 * n + lane15;
    #pragma unroll
    for (int j = 0; j < 4; ++j) {
      int t = 16 * ww + lhi * 4 + j;
      op[t * HDIM + h] = accO[n][j] * rinv[j];
    }
  }
}

extern "C" void kernel_launch(void* const* d_in, const int* in_sizes, int n_in,
                              void* d_out, int out_size, void* d_ws, size_t ws_size,
                              hipStream_t stream) {
  const float* x  = (const float*)d_in[0];
  const float* Wk = (const float*)d_in[1];
  const float* Wq = (const float*)d_in[2];
  const float* Wv = (const float*)d_in[3];
  float* out = (float*)d_out;
  unsigned short* wt = (unsigned short*)d_ws;  // 24 chunks x 12 KB = 288 KiB

  hipLaunchKernelGGL(prep_wt_kernel, dim3((3 * HDIM * CDIM + 255) / 256), dim3(256),
                     0, stream, Wk, Wq, Wv, wt);
  hipLaunchKernelGGL(head_fused_kernel, dim3(BATCHES / 2), dim3(512), 0, stream,
                     x, wt, out);
}